// Round 2
// baseline (239.051 us; speedup 1.0000x reference)
//
#include <hip/hip_runtime.h>
#include <hip/hip_fp16.h>
#include <math.h>

#define WAVE 64
#define KPAD 128   // padded K for W^T (zero-filled cols K..127)

typedef float        f32x4 __attribute__((ext_vector_type(4)));
typedef unsigned int u32x4 __attribute__((ext_vector_type(4)));

// fp32 convert-and-accumulate of one 16B chunk (8 halves) into a0..a7
#define ACC8S(q,s) { const __half2* hh = (const __half2*)&(q);              \
        float2 f0=__half22float2(hh[0]), f1=__half22float2(hh[1]);          \
        float2 f2=__half22float2(hh[2]), f3=__half22float2(hh[3]);          \
        a0+=(s)*f0.x; a1+=(s)*f0.y; a2+=(s)*f1.x; a3+=(s)*f1.y;             \
        a4+=(s)*f2.x; a5+=(s)*f2.y; a6+=(s)*f3.x; a7+=(s)*f3.y; }

// depth-2 fp16 add tree over 4 token-rows, then one fp32 convert-add
#define TREE4(qa,qb,qc,qd) {                                                 \
    const __half2* p0 = (const __half2*)&(qa);                               \
    const __half2* p1 = (const __half2*)&(qb);                               \
    const __half2* p2 = (const __half2*)&(qc);                               \
    const __half2* p3 = (const __half2*)&(qd);                               \
    __half2 s0 = __hadd2(__hadd2(p0[0], p1[0]), __hadd2(p2[0], p3[0]));      \
    __half2 s1 = __hadd2(__hadd2(p0[1], p1[1]), __hadd2(p2[1], p3[1]));      \
    __half2 s2 = __hadd2(__hadd2(p0[2], p1[2]), __hadd2(p2[2], p3[2]));      \
    __half2 s3 = __hadd2(__hadd2(p0[3], p1[3]), __hadd2(p2[3], p3[3]));      \
    float2 f0=__half22float2(s0), f1=__half22float2(s1);                     \
    float2 f2=__half22float2(s2), f3=__half22float2(s3);                     \
    a0+=f0.x; a1+=f0.y; a2+=f1.x; a3+=f1.y;                                  \
    a4+=f2.x; a5+=f2.y; a6+=f3.x; a7+=f3.y; }

// gather+accumulate one <=64-token chunk whose indices are in register idxv.
// 16-token (8 independent pair-loads) deep burst first, then 8, then pair tail.
#define GATHER_CHUNK(idxv, cnt)                                              \
  { int j = 0;                                                               \
    for (; j + 16 <= (cnt); j += 16) {                                       \
      int r0 = __shfl(idxv, j      + hsel);                                  \
      int r1 = __shfl(idxv, j + 2  + hsel);                                  \
      int r2 = __shfl(idxv, j + 4  + hsel);                                  \
      int r3 = __shfl(idxv, j + 6  + hsel);                                  \
      int r4 = __shfl(idxv, j + 8  + hsel);                                  \
      int r5 = __shfl(idxv, j + 10 + hsel);                                  \
      int r6 = __shfl(idxv, j + 12 + hsel);                                  \
      int r7 = __shfl(idxv, j + 14 + hsel);                                  \
      float4 q0 = we16[(size_t)r0 * 32 + c];                                 \
      float4 q1 = we16[(size_t)r1 * 32 + c];                                 \
      float4 q2 = we16[(size_t)r2 * 32 + c];                                 \
      float4 q3 = we16[(size_t)r3 * 32 + c];                                 \
      float4 q4 = we16[(size_t)r4 * 32 + c];                                 \
      float4 q5 = we16[(size_t)r5 * 32 + c];                                 \
      float4 q6 = we16[(size_t)r6 * 32 + c];                                 \
      float4 q7 = we16[(size_t)r7 * 32 + c];                                 \
      TREE4(q0, q1, q2, q3);                                                 \
      TREE4(q4, q5, q6, q7);                                                 \
    }                                                                        \
    if (j + 8 <= (cnt)) {                                                    \
      int r0 = __shfl(idxv, j     + hsel);                                   \
      int r1 = __shfl(idxv, j + 2 + hsel);                                   \
      int r2 = __shfl(idxv, j + 4 + hsel);                                   \
      int r3 = __shfl(idxv, j + 6 + hsel);                                   \
      float4 q0 = we16[(size_t)r0 * 32 + c];                                 \
      float4 q1 = we16[(size_t)r1 * 32 + c];                                 \
      float4 q2 = we16[(size_t)r2 * 32 + c];                                 \
      float4 q3 = we16[(size_t)r3 * 32 + c];                                 \
      TREE4(q0, q1, q2, q3);                                                 \
      j += 8;                                                                \
    }                                                                        \
    for (; j < (cnt); j += 2) {                                              \
      int srcl = j + hsel;                                                   \
      int rr = __shfl(idxv, (srcl < (cnt)) ? srcl : ((cnt) - 1));            \
      float s = (srcl < (cnt)) ? 1.0f : 0.0f;                                \
      float4 q = we16[(size_t)rr * 32 + c];                                  \
      ACC8S(q, s);                                                           \
    } }

// ---------------------------------------------------------------------------
// K1 (prep), grid sections:
//  [0, nArgBlk):       type_idx[b] = argmax_k typeTensor[b*K+k]  (wave/bag)
//  [+, nTrBlk):        WT[d][c] = fp16((c<K) ? W[c][d] : 0)
//  [+, nConvBlk):      weh = fp16(we)  (grid-strided, NT source loads)
// ---------------------------------------------------------------------------
__global__ __launch_bounds__(256) void k_prep(const float* __restrict__ tt,
                                              const float* __restrict__ lw,
                                              const float* __restrict__ we,
                                              int* __restrict__ type_idx,
                                              __half* __restrict__ wt,
                                              __half* __restrict__ weh,
                                              int B, int K, int D, int V,
                                              int nArgBlk, int nTrBlk) {
    int bx = blockIdx.x;
    if (bx < nArgBlk) {
        int wid  = threadIdx.x >> 6;
        int lane = threadIdx.x & 63;
        int b = bx * (blockDim.x >> 6) + wid;
        if (b >= B) return;
        float best = -INFINITY;
        int   bi   = 0x7fffffff;
        for (int k = lane; k < K; k += WAVE) {
            float v = tt[(size_t)b * K + k];
            if (v > best) { best = v; bi = k; }
        }
        for (int off = 32; off > 0; off >>= 1) {
            float ov = __shfl_down(best, off);
            int   oi = __shfl_down(bi, off);
            if (ov > best || (ov == best && oi < bi)) { best = ov; bi = oi; }
        }
        if (lane == 0) type_idx[b] = bi;
    } else if (bx < nArgBlk + nTrBlk) {
        int bid = bx - nArgBlk;
        int base = (bid * 256 + (int)threadIdx.x) * 4;
        int total = D * KPAD;
        for (int i = 0; i < 4; ++i) {
            int e = base + i;
            if (e >= total) break;
            int d = e >> 7;        // / KPAD
            int c = e & (KPAD - 1);
            wt[e] = (c < K) ? __float2half(lw[(size_t)c * D + d]) : __half(0.0f);
        }
    } else {
        int cid = bx - nArgBlk - nTrBlk;
        size_t n8 = ((size_t)V * D) >> 3;                  // groups of 8 floats
        size_t stride = ((size_t)gridDim.x - nArgBlk - nTrBlk) * 256;
        for (size_t i = (size_t)cid * 256 + threadIdx.x; i < n8; i += stride) {
            f32x4 v0 = __builtin_nontemporal_load((const f32x4*)(we + i * 8));
            f32x4 v1 = __builtin_nontemporal_load((const f32x4*)(we + i * 8 + 4));
            __half2 h0 = __float22half2_rn(make_float2(v0.x, v0.y));
            __half2 h1 = __float22half2_rn(make_float2(v0.z, v0.w));
            __half2 h2 = __float22half2_rn(make_float2(v1.x, v1.y));
            __half2 h3 = __float22half2_rn(make_float2(v1.z, v1.w));
            uint4 u;
            u.x = *reinterpret_cast<const unsigned int*>(&h0);
            u.y = *reinterpret_cast<const unsigned int*>(&h1);
            u.z = *reinterpret_cast<const unsigned int*>(&h2);
            u.w = *reinterpret_cast<const unsigned int*>(&h3);
            ((uint4*)weh)[i] = u;              // keep weh cached (gather input)
        }
    }
}

// ---------------------------------------------------------------------------
// K2 (fused): one block per bag, 4 waves round-robin over the bag's mentions.
// Latency-chain fixes vs prev version:
//  - all mention boundaries for the bag loaded ONCE into offv (one vector
//    load; t0/t1 become register shuffles, no per-mention offs latency)
//  - next mention's fs-index vector prefetched before consuming the current
//    mention's gather (fs load always in flight under ~1 mention of compute)
//  - 16-token deep burst: 8 independent pair-loads issued before any consume
// Online softmax accumulation in registers; 4-way LDS merge; fp16 W^T proj.
// ---------------------------------------------------------------------------
__global__ __launch_bounds__(256) void k_fused(const int* __restrict__ fs,
                                               const int* __restrict__ offs,
                                               const int* __restrict__ scope,
                                               const int* __restrict__ type_idx,
                                               const __half* __restrict__ weh,
                                               const float* __restrict__ lw,
                                               const __half* __restrict__ wt,
                                               float* __restrict__ out,
                                               int B, int M, int T, int D, int K) {
    __shared__ float  s_acc[4][256];   // per-wave online accumulator
    __shared__ float  s_stats[4][2];   // per-wave {runmax, runsum}
    __shared__ float  s_be[256];       // merged, normalized bag embedding
    __shared__ float2 s_part[4][64];   // projection partials per wave

    int b    = blockIdx.x;
    int wid  = threadIdx.x >> 6;
    int lane = threadIdx.x & 63;
    int c    = lane & 31;      // 16B-chunk (8 dims) within row
    int hsel = lane >> 5;      // 0: even token of pair, 1: odd token

    int m0 = scope[b];
    int m1 = scope[b + 1];

    // per-bag selected W row (uniform across block; hidden under first gather)
    int r = type_idx[b];
    const float4* wr = (const float4*)(lw + (size_t)r * D);
    float4 u0 = wr[c * 2];
    float4 u1 = wr[c * 2 + 1];

    const float4* we16 = (const float4*)weh;   // 16B = 8 halves; 32 chunks/row

    // hoist mention boundaries: one load covers offs[m0 .. m0+63]
    int oidx = m0 + lane;
    int offv = (oidx < M) ? offs[oidx] : T;
    // wave-uniform boundary fetch (shuffle fast path, global-load fallback)
    auto GETOFF = [&](int idx) -> int {
        int rel = idx - m0;
        if (rel < 64) return __shfl(offv, rel);
        return (idx < M) ? offs[idx] : T;
    };

    // online-softmax state (duplicated across half-waves)
    float mx = -INFINITY, sum = 0.f;
    float z0=0,z1=0,z2=0,z3=0,z4=0,z5=0,z6=0,z7=0;

    int m = m0 + wid;
    int t0c = 0, t1c = 0, pidx = 0;
    if (m < m1) {                       // prefetch first mention
        t0c = GETOFF(m);
        t1c = GETOFF(m + 1);
        int nn = t1c - t0c;
        pidx = (lane < nn) ? fs[t0c + lane] : 0;
    }

    while (m < m1) {
        int t0 = t0c, t1 = t1c, myidx = pidx;
        int mn = m + 4;
        if (mn < m1) {                  // prefetch next mention NOW
            t0c = GETOFF(mn);
            t1c = GETOFF(mn + 1);
            int nn2 = t1c - t0c;
            pidx = (lane < nn2) ? fs[t0c + lane] : 0;
        }

        float a0=0,a1=0,a2=0,a3=0,a4=0,a5=0,a6=0,a7=0;
        int nn0 = min(WAVE, t1 - t0);
        GATHER_CHUNK(myidx, nn0);
        for (int base = t0 + WAVE; base < t1; base += WAVE) {   // rare (>64 tok)
            int nn = min(WAVE, t1 - base);
            int idx2 = (lane < nn) ? fs[base + lane] : 0;
            GATHER_CHUNK(idx2, nn);
        }

        // merge the two half-wave token streams (lane c and c+32: same dims)
        a0 += __shfl_xor(a0, 32); a1 += __shfl_xor(a1, 32);
        a2 += __shfl_xor(a2, 32); a3 += __shfl_xor(a3, 32);
        a4 += __shfl_xor(a4, 32); a5 += __shfl_xor(a5, 32);
        a6 += __shfl_xor(a6, 32); a7 += __shfl_xor(a7, 32);

        float inv = 1.0f / (float)(t1 - t0);
        a0*=inv; a1*=inv; a2*=inv; a3*=inv; a4*=inv; a5*=inv; a6*=inv; a7*=inv;

        // selected score (all lanes end up with the full dot)
        float p = a0*u0.x + a1*u0.y + a2*u0.z + a3*u0.w
                + a4*u1.x + a5*u1.y + a6*u1.z + a7*u1.w;
        for (int off = 16; off > 0; off >>= 1) p += __shfl_xor(p, off);

        // online softmax accumulate (first iter: mx=-inf -> scale=0, z/sum=0)
        float nmx   = fmaxf(mx, p);
        float scale = __expf(mx - nmx);
        float w     = __expf(p - nmx);
        sum = sum * scale + w;
        z0 = z0*scale + w*a0; z1 = z1*scale + w*a1;
        z2 = z2*scale + w*a2; z3 = z3*scale + w*a3;
        z4 = z4*scale + w*a4; z5 = z5*scale + w*a5;
        z6 = z6*scale + w*a6; z7 = z7*scale + w*a7;
        mx = nmx;

        m = mn;
    }

    // ---- deposit per-wave state (lanes 0..31 own dims 8c..8c+7) ----
    if (hsel == 0) {
        ((float4*)s_acc[wid])[c * 2]     = make_float4(z0, z1, z2, z3);
        ((float4*)s_acc[wid])[c * 2 + 1] = make_float4(z4, z5, z6, z7);
    }
    if (lane == 0) { s_stats[wid][0] = mx; s_stats[wid][1] = sum; }
    __syncthreads();

    // ---- 4-way online-softmax merge; one dim per thread ----
    {
        int tid = threadIdx.x;
        float mx0 = s_stats[0][0], mx1 = s_stats[1][0];
        float mx2 = s_stats[2][0], mx3 = s_stats[3][0];
        float Mx = fmaxf(fmaxf(mx0, mx1), fmaxf(mx2, mx3));
        // empty wave: mx_w = -inf -> e_w = 0 (its sum/acc are 0 anyway)
        float e0 = __expf(mx0 - Mx), e1 = __expf(mx1 - Mx);
        float e2 = __expf(mx2 - Mx), e3 = __expf(mx3 - Mx);
        float S  = s_stats[0][1]*e0 + s_stats[1][1]*e1
                 + s_stats[2][1]*e2 + s_stats[3][1]*e3;
        float be = s_acc[0][tid]*e0 + s_acc[1][tid]*e1
                 + s_acc[2][tid]*e2 + s_acc[3][tid]*e3;
        s_be[tid] = be * (1.0f / S);
    }
    __syncthreads();

    // ---- projection via fp16 W^T: wave w covers dims [64w, 64w+64) ----
    const __half2* wt2 = (const __half2*)wt;    // [D][KPAD/2] half2
    const float* be = s_be + wid * 64;
    float2 o = make_float2(0.f, 0.f);
    int kc = lane;                              // half2 column (2kc, 2kc+1)
    #pragma unroll 4
    for (int d4 = 0; d4 < 16; ++d4) {
        float4 b4 = ((const float4*)be)[d4];    // LDS broadcast read
        int d = wid * 64 + (d4 << 2);
        float2 w0 = __half22float2(wt2[(size_t)(d + 0) * (KPAD/2) + kc]);
        float2 w1 = __half22float2(wt2[(size_t)(d + 1) * (KPAD/2) + kc]);
        float2 w2 = __half22float2(wt2[(size_t)(d + 2) * (KPAD/2) + kc]);
        float2 w3 = __half22float2(wt2[(size_t)(d + 3) * (KPAD/2) + kc]);
        o.x += b4.x*w0.x + b4.y*w1.x + b4.z*w2.x + b4.w*w3.x;
        o.y += b4.x*w0.y + b4.y*w1.y + b4.z*w2.y + b4.w*w3.y;
    }
    s_part[wid][kc] = o;
    __syncthreads();

    if (wid == 0) {
        float2 p0 = s_part[0][kc], p1 = s_part[1][kc];
        float2 p2 = s_part[2][kc], p3 = s_part[3][kc];
        float2 oo = make_float2(p0.x + p1.x + p2.x + p3.x,
                                p0.y + p1.y + p2.y + p3.y);
        int k0 = kc * 2;
        float* ob = out + (size_t)b * K;
        if (k0 + 1 < K) {
            ((float2*)ob)[kc] = oo;
        } else if (k0 < K) {
            ob[k0] = oo.x;
        }
    }
}

// ---------------------------------------------------------------------------
extern "C" void kernel_launch(void* const* d_in, const int* in_sizes, int n_in,
                              void* d_out, int out_size, void* d_ws, size_t ws_size,
                              hipStream_t stream) {
    const int*   feature_seq = (const int*)d_in[0];
    const int*   offset_seq  = (const int*)d_in[1];
    const int*   scope       = (const int*)d_in[2];
    const float* typeTensor  = (const float*)d_in[3];
    const float* word_emb    = (const float*)d_in[4];
    const float* linear_w    = (const float*)d_in[5];
    float* out = (float*)d_out;

    const int T = in_sizes[0];
    const int M = in_sizes[1];
    const int B = in_sizes[2] - 1;
    const int K = in_sizes[3] / B;       // 100
    const int D = in_sizes[5] / K;       // 256
    const int V = in_sizes[4] / D;       // 100000

    // workspace carve-up
    char* w = (char*)d_ws;
    auto align256 = [](size_t x) { return (x + 255) & ~(size_t)255; };
    int*    type_idx = (int*)w;    w += align256((size_t)B * sizeof(int));
    __half* wt       = (__half*)w; w += align256((size_t)D * KPAD * sizeof(__half));
    __half* weh      = (__half*)w; // V * D halves

    // K1: argmax + WT transpose + table fp32->fp16
    {
        int bagsPerBlock = 256 / WAVE;
        int nArgBlk  = (B + bagsPerBlock - 1) / bagsPerBlock;
        int nTrBlk   = (D * KPAD + 1023) / 1024;
        int nConvBlk = 4096;
        k_prep<<<nArgBlk + nTrBlk + nConvBlk, 256, 0, stream>>>(
            typeTensor, linear_w, word_emb, type_idx, wt, weh,
            B, K, D, V, nArgBlk, nTrBlk);
    }
    // K2: fused mention means + per-bag online softmax + weighted sum + proj
    {
        k_fused<<<B, 256, 0, stream>>>(feature_seq, offset_seq, scope, type_idx,
                                       weh, linear_w, wt, out, B, M, T, D, K);
    }
}

// Round 3
// 227.624 us; speedup vs baseline: 1.0502x; 1.0502x over previous
//
#include <hip/hip_runtime.h>
#include <hip/hip_fp16.h>
#include <math.h>

#define WAVE 64
#define KPAD 128   // padded K for W^T (zero-filled cols K..127)
#define NGRP 16    // 32-lane mention groups per block (512 threads)

typedef float        f32x4 __attribute__((ext_vector_type(4)));
typedef unsigned int u32x4 __attribute__((ext_vector_type(4)));

// fp32 convert-and-accumulate of one 16B chunk (8 halves) into a0..a7
#define ACC8S(q,s) { const __half2* hh = (const __half2*)&(q);              \
        float2 f0=__half22float2(hh[0]), f1=__half22float2(hh[1]);          \
        float2 f2=__half22float2(hh[2]), f3=__half22float2(hh[3]);          \
        a0+=(s)*f0.x; a1+=(s)*f0.y; a2+=(s)*f1.x; a3+=(s)*f1.y;             \
        a4+=(s)*f2.x; a5+=(s)*f2.y; a6+=(s)*f3.x; a7+=(s)*f3.y; }

// depth-2 fp16 add tree over 4 token-rows, then one fp32 convert-add
#define TREE4(qa,qb,qc,qd) {                                                 \
    const __half2* p0 = (const __half2*)&(qa);                               \
    const __half2* p1 = (const __half2*)&(qb);                               \
    const __half2* p2 = (const __half2*)&(qc);                               \
    const __half2* p3 = (const __half2*)&(qd);                               \
    __half2 s0 = __hadd2(__hadd2(p0[0], p1[0]), __hadd2(p2[0], p3[0]));      \
    __half2 s1 = __hadd2(__hadd2(p0[1], p1[1]), __hadd2(p2[1], p3[1]));      \
    __half2 s2 = __hadd2(__hadd2(p0[2], p1[2]), __hadd2(p2[2], p3[2]));      \
    __half2 s3 = __hadd2(__hadd2(p0[3], p1[3]), __hadd2(p2[3], p3[3]));      \
    float2 f0=__half22float2(s0), f1=__half22float2(s1);                     \
    float2 f2=__half22float2(s2), f3=__half22float2(s3);                     \
    a0+=f0.x; a1+=f0.y; a2+=f1.x; a3+=f1.y;                                  \
    a4+=f2.x; a5+=f2.y; a6+=f3.x; a7+=f3.y; }

// gather+accumulate one <=32-token chunk (indices in idxv, per 32-lane group).
// One full 512B row per load instruction (32 lanes x 16B). 4-deep ILP burst.
#define GATHER32(idxv, cnt)                                                  \
  { int j = 0;                                                               \
    for (; j + 4 <= (cnt); j += 4) {                                         \
      int r0 = __shfl(idxv, base32 + j);                                     \
      int r1 = __shfl(idxv, base32 + j + 1);                                 \
      int r2 = __shfl(idxv, base32 + j + 2);                                 \
      int r3 = __shfl(idxv, base32 + j + 3);                                 \
      float4 q0 = we16[(size_t)r0 * 32 + c];                                 \
      float4 q1 = we16[(size_t)r1 * 32 + c];                                 \
      float4 q2 = we16[(size_t)r2 * 32 + c];                                 \
      float4 q3 = we16[(size_t)r3 * 32 + c];                                 \
      TREE4(q0, q1, q2, q3);                                                 \
    }                                                                        \
    for (; j < (cnt); ++j) {                                                 \
      int rr = __shfl(idxv, base32 + j);                                     \
      float4 q = we16[(size_t)rr * 32 + c];                                  \
      ACC8S(q, 1.0f);                                                        \
    } }

// ---------------------------------------------------------------------------
// K1 (prep), grid sections:
//  [0, nArgBlk):       type_idx[b] = argmax_k typeTensor[b*K+k]  (wave/bag)
//  [+, nTrBlk):        WT[d][c] = fp16((c<K) ? W[c][d] : 0)
//  [+, nConvBlk):      weh = fp16(we)  (grid-strided, NT source loads)
// ---------------------------------------------------------------------------
__global__ __launch_bounds__(256) void k_prep(const float* __restrict__ tt,
                                              const float* __restrict__ lw,
                                              const float* __restrict__ we,
                                              int* __restrict__ type_idx,
                                              __half* __restrict__ wt,
                                              __half* __restrict__ weh,
                                              int B, int K, int D, int V,
                                              int nArgBlk, int nTrBlk) {
    int bx = blockIdx.x;
    if (bx < nArgBlk) {
        int wid  = threadIdx.x >> 6;
        int lane = threadIdx.x & 63;
        int b = bx * (blockDim.x >> 6) + wid;
        if (b >= B) return;
        float best = -INFINITY;
        int   bi   = 0x7fffffff;
        for (int k = lane; k < K; k += WAVE) {
            float v = tt[(size_t)b * K + k];
            if (v > best) { best = v; bi = k; }
        }
        for (int off = 32; off > 0; off >>= 1) {
            float ov = __shfl_down(best, off);
            int   oi = __shfl_down(bi, off);
            if (ov > best || (ov == best && oi < bi)) { best = ov; bi = oi; }
        }
        if (lane == 0) type_idx[b] = bi;
    } else if (bx < nArgBlk + nTrBlk) {
        int bid = bx - nArgBlk;
        int base = (bid * 256 + (int)threadIdx.x) * 4;
        int total = D * KPAD;
        for (int i = 0; i < 4; ++i) {
            int e = base + i;
            if (e >= total) break;
            int d = e >> 7;        // / KPAD
            int c = e & (KPAD - 1);
            wt[e] = (c < K) ? __float2half(lw[(size_t)c * D + d]) : __half(0.0f);
        }
    } else {
        int cid = bx - nArgBlk - nTrBlk;
        size_t n8 = ((size_t)V * D) >> 3;                  // groups of 8 floats
        size_t stride = ((size_t)gridDim.x - nArgBlk - nTrBlk) * 256;
        for (size_t i = (size_t)cid * 256 + threadIdx.x; i < n8; i += stride) {
            f32x4 v0 = __builtin_nontemporal_load((const f32x4*)(we + i * 8));
            f32x4 v1 = __builtin_nontemporal_load((const f32x4*)(we + i * 8 + 4));
            __half2 h0 = __float22half2_rn(make_float2(v0.x, v0.y));
            __half2 h1 = __float22half2_rn(make_float2(v0.z, v0.w));
            __half2 h2 = __float22half2_rn(make_float2(v1.x, v1.y));
            __half2 h3 = __float22half2_rn(make_float2(v1.z, v1.w));
            uint4 u;
            u.x = *reinterpret_cast<const unsigned int*>(&h0);
            u.y = *reinterpret_cast<const unsigned int*>(&h1);
            u.z = *reinterpret_cast<const unsigned int*>(&h2);
            u.w = *reinterpret_cast<const unsigned int*>(&h3);
            ((uint4*)weh)[i] = u;              // keep weh cached (gather input)
        }
    }
}

// ---------------------------------------------------------------------------
// K2 (fused): one block (512 thr = 8 waves = 16 half-wave groups) per bag.
// Each 32-lane group owns mentions m0+g, m0+g+16, ... :
//   - one full 512B embedding row per load instruction (32 lanes x 16B)
//   - mean + selected score + ONLINE softmax accumulation, all per-group
// Tail fix vs prev: 16 concurrent mention chains per bag (was 4) -> worst-bag
// serial chain drops ~4x. TLP (32 waves/CU via launch_bounds) hides gather
// latency instead of deep per-wave ILP (which only raised VGPR).
// 16-way LDS merge of (max,sum,acc); projection via fp16 W^T over 8 waves.
// ---------------------------------------------------------------------------
__global__ __launch_bounds__(512, 8) void k_fused(const int* __restrict__ fs,
                                                  const int* __restrict__ offs,
                                                  const int* __restrict__ scope,
                                                  const int* __restrict__ type_idx,
                                                  const __half* __restrict__ weh,
                                                  const float* __restrict__ lw,
                                                  const __half* __restrict__ wt,
                                                  float* __restrict__ out,
                                                  int B, int M, int T, int D, int K) {
    __shared__ float  s_acc[NGRP][256];   // per-group online accumulator
    __shared__ float  s_stats[NGRP][2];   // per-group {runmax, runsum}
    __shared__ float  s_be[256];          // merged, normalized bag embedding
    __shared__ float2 s_part[8][64];      // projection partials per wave

    int b      = blockIdx.x;
    int tid    = threadIdx.x;
    int group  = tid >> 5;        // 0..15: mention group
    int c      = tid & 31;        // 16B-chunk (8 dims) within row
    int base32 = tid & 32;        // this half-wave's lane base within the wave

    int m0 = scope[b];
    int m1 = scope[b + 1];

    // per-bag selected W row (uniform across block; hidden under first gather)
    int r = type_idx[b];
    const float4* wr = (const float4*)(lw + (size_t)r * D);
    float4 u0 = wr[c * 2];
    float4 u1 = wr[c * 2 + 1];

    const float4* we16 = (const float4*)weh;   // 16B = 8 halves; 32 chunks/row

    // online-softmax state per 32-lane group
    float mx = -INFINITY, sum = 0.f;
    float z0=0,z1=0,z2=0,z3=0,z4=0,z5=0,z6=0,z7=0;

    for (int m = m0 + group; m < m1; m += NGRP) {
        int t0 = offs[m];
        int t1 = (m + 1 < M) ? offs[m + 1] : T;

        float a0=0,a1=0,a2=0,a3=0,a4=0,a5=0,a6=0,a7=0;
        for (int base = t0; base < t1; base += 32) {
            int nn = min(32, t1 - base);
            int idxv = (c < nn) ? fs[base + c] : 0;
            GATHER32(idxv, nn);
        }

        float inv = 1.0f / (float)(t1 - t0);
        a0*=inv; a1*=inv; a2*=inv; a3*=inv; a4*=inv; a5*=inv; a6*=inv; a7*=inv;

        // selected score: per-lane partial dot, reduce over the 32-lane group
        float p = a0*u0.x + a1*u0.y + a2*u0.z + a3*u0.w
                + a4*u1.x + a5*u1.y + a6*u1.z + a7*u1.w;
        for (int off = 16; off > 0; off >>= 1) p += __shfl_xor(p, off);

        // online softmax accumulate (first iter: mx=-inf -> scale=0, z/sum=0)
        float nmx   = fmaxf(mx, p);
        float scale = __expf(mx - nmx);
        float w     = __expf(p - nmx);
        sum = sum * scale + w;
        z0 = z0*scale + w*a0; z1 = z1*scale + w*a1;
        z2 = z2*scale + w*a2; z3 = z3*scale + w*a3;
        z4 = z4*scale + w*a4; z5 = z5*scale + w*a5;
        z6 = z6*scale + w*a6; z7 = z7*scale + w*a7;
        mx = nmx;
    }

    // ---- deposit per-group state (lane c owns dims 8c..8c+7) ----
    ((float4*)s_acc[group])[c * 2]     = make_float4(z0, z1, z2, z3);
    ((float4*)s_acc[group])[c * 2 + 1] = make_float4(z4, z5, z6, z7);
    if (c == 0) { s_stats[group][0] = mx; s_stats[group][1] = sum; }
    __syncthreads();

    // ---- 16-way online-softmax merge; one dim per thread (tid<256) ----
    if (tid < 256) {
        float Mx = -INFINITY;
        #pragma unroll
        for (int g = 0; g < NGRP; ++g) Mx = fmaxf(Mx, s_stats[g][0]);
        // empty group: mx_g = -inf -> e_g = 0 (its sum/acc are 0 anyway);
        // bag is never empty (scope strictly increasing), so Mx > -inf
        float S = 0.f, be = 0.f;
        #pragma unroll
        for (int g = 0; g < NGRP; ++g) {
            float e = __expf(s_stats[g][0] - Mx);
            S  += s_stats[g][1] * e;
            be += s_acc[g][tid] * e;
        }
        s_be[tid] = be * (1.0f / S);
    }
    __syncthreads();

    // ---- projection via fp16 W^T: wave w covers dims [32w, 32w+32) ----
    int wid  = tid >> 6;
    int lane = tid & 63;
    const __half2* wt2 = (const __half2*)wt;    // [D][KPAD/2] half2
    const float* bep = s_be + wid * 32;
    float2 o = make_float2(0.f, 0.f);
    int kc = lane;                              // half2 column (2kc, 2kc+1)
    #pragma unroll
    for (int d4 = 0; d4 < 8; ++d4) {
        float4 b4 = ((const float4*)bep)[d4];   // LDS broadcast read
        int d = wid * 32 + (d4 << 2);
        float2 w0 = __half22float2(wt2[(size_t)(d + 0) * (KPAD/2) + kc]);
        float2 w1 = __half22float2(wt2[(size_t)(d + 1) * (KPAD/2) + kc]);
        float2 w2 = __half22float2(wt2[(size_t)(d + 2) * (KPAD/2) + kc]);
        float2 w3 = __half22float2(wt2[(size_t)(d + 3) * (KPAD/2) + kc]);
        o.x += b4.x*w0.x + b4.y*w1.x + b4.z*w2.x + b4.w*w3.x;
        o.y += b4.x*w0.y + b4.y*w1.y + b4.z*w2.y + b4.w*w3.y;
    }
    s_part[wid][kc] = o;
    __syncthreads();

    if (wid == 0) {
        float2 oo = make_float2(0.f, 0.f);
        #pragma unroll
        for (int w8 = 0; w8 < 8; ++w8) {
            float2 pw = s_part[w8][kc];
            oo.x += pw.x; oo.y += pw.y;
        }
        int k0 = kc * 2;
        float* ob = out + (size_t)b * K;
        if (k0 + 1 < K) {
            ((float2*)ob)[kc] = oo;
        } else if (k0 < K) {
            ob[k0] = oo.x;
        }
    }
}

// ---------------------------------------------------------------------------
extern "C" void kernel_launch(void* const* d_in, const int* in_sizes, int n_in,
                              void* d_out, int out_size, void* d_ws, size_t ws_size,
                              hipStream_t stream) {
    const int*   feature_seq = (const int*)d_in[0];
    const int*   offset_seq  = (const int*)d_in[1];
    const int*   scope       = (const int*)d_in[2];
    const float* typeTensor  = (const float*)d_in[3];
    const float* word_emb    = (const float*)d_in[4];
    const float* linear_w    = (const float*)d_in[5];
    float* out = (float*)d_out;

    const int T = in_sizes[0];
    const int M = in_sizes[1];
    const int B = in_sizes[2] - 1;
    const int K = in_sizes[3] / B;       // 100
    const int D = in_sizes[5] / K;       // 256
    const int V = in_sizes[4] / D;       // 100000

    // workspace carve-up
    char* w = (char*)d_ws;
    auto align256 = [](size_t x) { return (x + 255) & ~(size_t)255; };
    int*    type_idx = (int*)w;    w += align256((size_t)B * sizeof(int));
    __half* wt       = (__half*)w; w += align256((size_t)D * KPAD * sizeof(__half));
    __half* weh      = (__half*)w; // V * D halves

    // K1: argmax + WT transpose + table fp32->fp16
    {
        int bagsPerBlock = 256 / WAVE;
        int nArgBlk  = (B + bagsPerBlock - 1) / bagsPerBlock;
        int nTrBlk   = (D * KPAD + 1023) / 1024;
        int nConvBlk = 4096;
        k_prep<<<nArgBlk + nTrBlk + nConvBlk, 256, 0, stream>>>(
            typeTensor, linear_w, word_emb, type_idx, wt, weh,
            B, K, D, V, nArgBlk, nTrBlk);
    }
    // K2: fused mention means + per-bag online softmax + weighted sum + proj
    {
        k_fused<<<B, 512, 0, stream>>>(feature_seq, offset_seq, scope, type_idx,
                                       weh, linear_w, wt, out, B, M, T, D, K);
    }
}